// Round 3
// baseline (12790.827 us; speedup 1.0000x reference)
//
#include <hip/hip_runtime.h>
#include <hip/hip_bf16.h>

#define BB_ 16
#define T_ 2048
#define DIN_ 64
#define D_ 512
#define DI_ 1024
#define N_ 16
#define DC_ 4
#define R_ 32
#define L_ 3
#define DOUT_ 128

__device__ __forceinline__ float silu_f(float x) { return x / (1.f + __expf(-x)); }

// ACT: 0 = none, 1 = +bias, 2 = +bias then softplus, 3 = +bias then tanh
template<int ACT>
__global__ __launch_bounds__(256) void gemm_t128(
    const float* __restrict__ A, int lda,
    const float* __restrict__ B, int ldb,
    const float* __restrict__ bias,
    float* __restrict__ C, int ldc, int K)
{
    __shared__ __align__(16) float As[8][128];
    __shared__ __align__(16) float Bs[8][128];
    const int tid  = threadIdx.x;
    const int row0 = blockIdx.y << 7;
    const int col0 = blockIdx.x << 7;
    const int tx = tid & 15, ty = tid >> 4;

    float acc[8][8];
#pragma unroll
    for (int i = 0; i < 8; ++i)
#pragma unroll
        for (int j = 0; j < 8; ++j) acc[i][j] = 0.f;

    const int arow = tid >> 1;
    const int acol = (tid & 1) << 2;
    const float* Ap = A + (size_t)(row0 + arow) * lda + acol;
    const float* Bp = B + (size_t)(col0 + arow) * ldb + acol;

    for (int k0 = 0; k0 < K; k0 += 8) {
        const float4 av = *(const float4*)(Ap + k0);
        const float4 bv = *(const float4*)(Bp + k0);
        __syncthreads();
        As[acol + 0][arow] = av.x; As[acol + 1][arow] = av.y;
        As[acol + 2][arow] = av.z; As[acol + 3][arow] = av.w;
        Bs[acol + 0][arow] = bv.x; Bs[acol + 1][arow] = bv.y;
        Bs[acol + 2][arow] = bv.z; Bs[acol + 3][arow] = bv.w;
        __syncthreads();
#pragma unroll
        for (int k = 0; k < 8; ++k) {
            float a[8], b[8];
            *(float4*)&a[0] = *(const float4*)&As[k][ty << 3];
            *(float4*)&a[4] = *(const float4*)&As[k][(ty << 3) + 4];
            *(float4*)&b[0] = *(const float4*)&Bs[k][tx << 3];
            *(float4*)&b[4] = *(const float4*)&Bs[k][(tx << 3) + 4];
#pragma unroll
            for (int i = 0; i < 8; ++i)
#pragma unroll
                for (int j = 0; j < 8; ++j)
                    acc[i][j] = fmaf(a[i], b[j], acc[i][j]);
        }
    }

    float bv8[8];
#pragma unroll
    for (int j = 0; j < 8; ++j) bv8[j] = (ACT >= 1) ? bias[col0 + (tx << 3) + j] : 0.f;

#pragma unroll
    for (int i = 0; i < 8; ++i) {
        float* Cp = C + (size_t)(row0 + (ty << 3) + i) * ldc + col0 + (tx << 3);
        float v[8];
#pragma unroll
        for (int j = 0; j < 8; ++j) {
            float t = (ACT >= 1) ? (acc[i][j] + bv8[j]) : acc[i][j];
            if (ACT == 2) t = (t > 20.f) ? t : log1pf(__expf(t));
            if (ACT == 3) t = tanhf(t);
            v[j] = t;
        }
        *(float4*)(Cp)     = make_float4(v[0], v[1], v[2], v[3]);
        *(float4*)(Cp + 4) = make_float4(v[4], v[5], v[6], v[7]);
    }
}

// 128x64 tile variant for N=64 (dbc GEMM)
template<int ACT>
__global__ __launch_bounds__(256) void gemm_t64n(
    const float* __restrict__ A, int lda,
    const float* __restrict__ B, int ldb,
    const float* __restrict__ bias,
    float* __restrict__ C, int ldc, int K)
{
    __shared__ __align__(16) float As[8][128];
    __shared__ __align__(16) float Bs[8][64];
    const int tid  = threadIdx.x;
    const int row0 = blockIdx.y << 7;
    const int col0 = blockIdx.x << 6;
    const int tx = tid & 15, ty = tid >> 4;

    float acc[8][4];
#pragma unroll
    for (int i = 0; i < 8; ++i)
#pragma unroll
        for (int j = 0; j < 4; ++j) acc[i][j] = 0.f;

    const int arow = tid >> 1, acol = (tid & 1) << 2;
    const int brow = tid >> 2, bcol = (tid & 3) << 1;
    const float* Ap = A + (size_t)(row0 + arow) * lda + acol;
    const float* Bp = B + (size_t)(col0 + brow) * ldb + bcol;

    for (int k0 = 0; k0 < K; k0 += 8) {
        const float4 av = *(const float4*)(Ap + k0);
        const float2 bv = *(const float2*)(Bp + k0);
        __syncthreads();
        As[acol + 0][arow] = av.x; As[acol + 1][arow] = av.y;
        As[acol + 2][arow] = av.z; As[acol + 3][arow] = av.w;
        Bs[bcol + 0][brow] = bv.x;
        Bs[bcol + 1][brow] = bv.y;
        __syncthreads();
#pragma unroll
        for (int k = 0; k < 8; ++k) {
            float a[8], b[4];
            *(float4*)&a[0] = *(const float4*)&As[k][ty << 3];
            *(float4*)&a[4] = *(const float4*)&As[k][(ty << 3) + 4];
            *(float4*)&b[0] = *(const float4*)&Bs[k][tx << 2];
#pragma unroll
            for (int i = 0; i < 8; ++i)
#pragma unroll
                for (int j = 0; j < 4; ++j)
                    acc[i][j] = fmaf(a[i], b[j], acc[i][j]);
        }
    }

#pragma unroll
    for (int i = 0; i < 8; ++i) {
        float* Cp = C + (size_t)(row0 + (ty << 3) + i) * ldc + col0 + (tx << 2);
        *(float4*)(Cp) = make_float4(acc[i][0], acc[i][1], acc[i][2], acc[i][3]);
    }
}

// depthwise causal conv (DC=4) + bias + SiLU. Reads xin = xz[:, :DI_].
__global__ __launch_bounds__(256) void conv_silu_kernel(
    const float* __restrict__ xz, const float* __restrict__ cw,
    const float* __restrict__ cb, float* __restrict__ u)
{
    const size_t idx = (size_t)blockIdx.x * 256 + threadIdx.x; // m*DI + c
    const int c = (int)(idx & (DI_ - 1));
    const size_t m = idx >> 10;
    const int t = (int)(m & (T_ - 1));
    const float w0 = cw[c * DC_ + 0], w1 = cw[c * DC_ + 1];
    const float w2 = cw[c * DC_ + 2], w3 = cw[c * DC_ + 3];
    const float* xr = xz + m * 2048 + c;
    float acc = cb[c];
    if (t >= 3) acc = fmaf(xr[-3 * 2048], w0, acc);
    if (t >= 2) acc = fmaf(xr[-2 * 2048], w1, acc);
    if (t >= 1) acc = fmaf(xr[-1 * 2048], w2, acc);
    acc = fmaf(xr[0], w3, acc);
    u[idx] = silu_f(acc);
}

// selective scan: thread owns (b, d); 16 states in registers; B/C staged in LDS.
// delta lives at xz[m*2048 + d] (in-place over xin); z at xz[m*2048 + 1024 + d].
// Fuses y += u*Dp and g = y * silu(z); writes g over delta (same location).
#define TC_ 128
__global__ __launch_bounds__(256) void scan_kernel(
    const float* __restrict__ u, float* __restrict__ xz,
    const float* __restrict__ dbc, const float* __restrict__ A_log_l,
    const float* __restrict__ Dp_l)
{
    __shared__ float sB[TC_][N_];
    __shared__ float sC[TC_][N_];
    const int tid = threadIdx.x;
    const int b = blockIdx.x;
    const int d = (blockIdx.y << 8) + tid;

    float a2[N_], hs[N_];
#pragma unroll
    for (int n = 0; n < N_; ++n) {
        a2[n] = -__expf(A_log_l[d * N_ + n]) * 1.44269504f; // A * log2(e)
        hs[n] = 0.f;
    }
    const float Dpd = Dp_l[d];

    for (int ch = 0; ch < T_ / TC_; ++ch) {
        __syncthreads();
        for (int i = tid; i < TC_ * N_; i += 256) {
            const int tl = i >> 4, n = i & 15;
            const size_t base = ((size_t)b * T_ + (size_t)ch * TC_ + tl) * 64;
            sB[tl][n] = dbc[base + 32 + n];
            sC[tl][n] = dbc[base + 48 + n];
        }
        __syncthreads();
        for (int tt = 0; tt < TC_; ++tt) {
            const size_t m = (size_t)b * T_ + (size_t)ch * TC_ + tt;
            const float dl = xz[m * 2048 + d];          // delta (in xin slot)
            const float uv = u[m * DI_ + d];
            const float du = dl * uv;
            float yv = 0.f;
#pragma unroll
            for (int n = 0; n < N_; ++n) {
                const float dA = exp2f(dl * a2[n]);
                hs[n] = fmaf(dA, hs[n], du * sB[tt][n]);
                yv = fmaf(hs[n], sC[tt][n], yv);
            }
            yv = fmaf(uv, Dpd, yv);
            const float zv = xz[m * 2048 + DI_ + d];
            xz[m * 2048 + d] = yv * silu_f(zv);          // g over delta
        }
    }
}

extern "C" void kernel_launch(void* const* d_in, const int* in_sizes, int n_in,
                              void* d_out, int out_size, void* d_ws, size_t ws_size,
                              hipStream_t stream) {
    const float* x     = (const float*)d_in[0];
    const float* Wi    = (const float*)d_in[1];
    const float* bi    = (const float*)d_in[2];
    const float* Win   = (const float*)d_in[3];
    const float* convw = (const float*)d_in[4];
    const float* convb = (const float*)d_in[5];
    const float* Wx    = (const float*)d_in[6];
    const float* Wdt   = (const float*)d_in[7];
    const float* bdt   = (const float*)d_in[8];
    const float* A_log = (const float*)d_in[9];
    const float* Dp    = (const float*)d_in[10];
    const float* Wout  = (const float*)d_in[11];
    const float* Wo    = (const float*)d_in[12];
    const float* bo    = (const float*)d_in[13];
    float* out = (float*)d_out;

    // Per-row workspace floats: h(512) + xz(2048) + u(1024) + dbc(64) = 3648.
    // delta & g live in-place over the xin half of xz. Pick the largest batch
    // chunk CB that fits ws_size (deterministic: ws_size is fixed).
    const size_t rowf = (size_t)D_ + 2048 + DI_ + 64;
    int CB = BB_;
    while (CB > 1 && (size_t)CB * T_ * rowf * sizeof(float) > ws_size) CB >>= 1;
    const size_t Mc = (size_t)CB * T_;   // rows per chunk

    const dim3 blk(256);
    const int rowTiles = (int)(Mc / 128);

    for (int c = 0; c < BB_ / CB; ++c) {
        const float* x_c = x + (size_t)c * Mc * DIN_;
        float* out_c     = out + (size_t)c * Mc * DOUT_;

        float* ws  = (float*)d_ws;
        float* h   = ws;                         // Mc*512
        float* xz  = h  + Mc * D_;               // Mc*2048
        float* u   = xz + Mc * 2048;             // Mc*1024
        float* dbc = u  + Mc * DI_;              // Mc*64

        // h = x @ Wi.T + bi   (Mc x 512, K=64)
        gemm_t128<1><<<dim3(D_ / 128, rowTiles), blk, 0, stream>>>(
            x_c, DIN_, Wi, DIN_, bi, h, D_, DIN_);

        for (int l = 0; l < L_; ++l) {
            const float* Win_l  = Win  + (size_t)l * 2 * DI_ * D_;
            const float* cw_l   = convw + (size_t)l * DI_ * DC_;
            const float* cb_l   = convb + (size_t)l * DI_;
            const float* Wx_l   = Wx   + (size_t)l * (R_ + 2 * N_) * DI_;
            const float* Wdt_l  = Wdt  + (size_t)l * DI_ * R_;
            const float* bdt_l  = bdt  + (size_t)l * DI_;
            const float* Alog_l = A_log + (size_t)l * DI_ * N_;
            const float* Dp_l   = Dp   + (size_t)l * DI_;
            const float* Wout_l = Wout + (size_t)l * D_ * DI_;

            // xz = h @ Win.T   (Mc x 2048, K=512)
            gemm_t128<0><<<dim3(2048 / 128, rowTiles), blk, 0, stream>>>(
                h, D_, Win_l, D_, nullptr, xz, 2048, D_);

            // u = silu(causal_dwconv(xin) + cb)
            conv_silu_kernel<<<dim3((unsigned)(Mc * DI_ / 256)), blk, 0, stream>>>(
                xz, cw_l, cb_l, u);

            // dbc = u @ Wx.T   (Mc x 64, K=1024)
            gemm_t64n<0><<<dim3(1, rowTiles), blk, 0, stream>>>(
                u, DI_, Wx_l, DI_, nullptr, dbc, 64, DI_);

            // delta = softplus(dt @ Wdt.T + bdt), written into xz[:, :1024]
            // (xin is dead after the conv) with ldc = 2048.
            gemm_t128<2><<<dim3(DI_ / 128, rowTiles), blk, 0, stream>>>(
                dbc, 64, Wdt_l, R_, bdt_l, xz, 2048, R_);

            // selective scan + epilogue; g written over delta in xz[:, :1024]
            scan_kernel<<<dim3(CB, DI_ / 256), blk, 0, stream>>>(
                u, xz, dbc, Alog_l, Dp_l);

            // h = g @ Wout.T   (Mc x 512, K=1024); A = xz with lda=2048
            gemm_t128<0><<<dim3(D_ / 128, rowTiles), blk, 0, stream>>>(
                xz, 2048, Wout_l, DI_, nullptr, h, D_, DI_);
        }

        // out = tanh(h @ Wo.T + bo)   (Mc x 128, K=512)
        gemm_t128<3><<<dim3(DOUT_ / 128, rowTiles), blk, 0, stream>>>(
            h, D_, Wo, D_, bo, out_c, DOUT_, D_);
    }
}